// Round 7
// baseline (9734.794 us; speedup 1.0000x reference)
//
#include <hip/hip_runtime.h>
#include <hip/hip_bf16.h>
#include <math.h>

// ---------------------------------------------------------------------------
// DecoderTARDIS forward, fp32 — v5: ZERO-SYNC per-batch persistent blocks.
// Rounds 3-6 lesson: all cross-block structures (barriers/coherent traffic/
// phase skew) cost ~95us/step regardless of protocol. The recurrence is fully
// per-batch independent; the only shared operand is the weights. v5: one
// block owns one batch for all 32 steps; weights are re-streamed from
// L2/LLC (one copy per XCD, shared by its 16 blocks); beta==0 skips the 4MB
// W_h2c stream, alpha==0 skips Wr2c (exact: hard-sigmoid gates are 0/1).
// All recurrent state lives in LDS. No barriers, no atomics, 4 launches.
// ---------------------------------------------------------------------------

static constexpr int LL    = 32;
static constexpr int BB    = 128;
static constexpr int ID    = 512;
static constexpr int HD    = 1024;
static constexpr int NS    = 512;
static constexpr int AA    = 128;
static constexpr int CCd   = 128;
static constexpr int AC    = 256;

// ------------------------------ threefry -----------------------------------
__device__ __forceinline__ uint32_t rotl32(uint32_t x, uint32_t r) {
  return (x << r) | (x >> (32u - r));
}

__device__ __forceinline__ void threefry2x32(uint32_t k0, uint32_t k1,
                                             uint32_t x0, uint32_t x1,
                                             uint32_t& o0, uint32_t& o1) {
  uint32_t ks0 = k0, ks1 = k1, ks2 = 0x1BD11BDAu ^ k0 ^ k1;
  x0 += ks0; x1 += ks1;
#define TFR(r) { x0 += x1; x1 = rotl32(x1, r); x1 ^= x0; }
  TFR(13u) TFR(15u) TFR(26u) TFR(6u)   x0 += ks1; x1 += ks2 + 1u;
  TFR(17u) TFR(29u) TFR(16u) TFR(24u)  x0 += ks2; x1 += ks0 + 2u;
  TFR(13u) TFR(15u) TFR(26u) TFR(6u)   x0 += ks0; x1 += ks1 + 3u;
  TFR(17u) TFR(29u) TFR(16u) TFR(24u)  x0 += ks1; x1 += ks2 + 4u;
  TFR(13u) TFR(15u) TFR(26u) TFR(6u)   x0 += ks2; x1 += ks0 + 5u;
#undef TFR
  o0 = x0; o1 = x1;
}

__device__ __forceinline__ float bits_to_gumbel(uint32_t bits) {
  uint32_t v = (bits >> 9) | 0x3F800000u;
  float f = __uint_as_float(v) - 1.0f;
  if (f <= 0.0f) f = 1.17549435e-38f;
  return -logf(-logf(f));
}

__device__ __forceinline__ float fast_tanh(float x) {
  float e = __expf(2.0f * x);
  return 1.0f - 2.0f / (e + 1.0f);
}

// ------------------------------ prologue -----------------------------------
__global__ void addrw_kernel(const float* __restrict__ mem_bias,
                             const float* __restrict__ Wm2w,
                             float* __restrict__ addrW, float* __restrict__ addrWT) {
  int idx = blockIdx.x * blockDim.x + threadIdx.x;
  if (idx >= NS * AC) return;
  int n = idx / AC, m = idx % AC;
  float acc = 0.0f;
  for (int k = 0; k < AA; k++) acc += mem_bias[(size_t)n * AC + k] * Wm2w[(size_t)k * AC + m];
  addrW[(size_t)n * AC + m] = acc;
  addrWT[(size_t)m * NS + n] = acc;
}

// generic fp32 GEMM: C(M x Nw) = A(M x K) @ W(K x Nw); 128x64 tile, 8x4/thr
__global__ __launch_bounds__(256) void gemm_big(const float* __restrict__ A,
                                                const float* __restrict__ W,
                                                float* __restrict__ C,
                                                int K, int Nw) {
  __shared__ float sA[32][132];
  __shared__ float sB[32][68];
  const int tx = threadIdx.x & 15, ty = threadIdx.x >> 4;
  const int m0 = blockIdx.x * 128, n0 = blockIdx.y * 64;
  float acc[8][4] = {};
  for (int k0 = 0; k0 < K; k0 += 32) {
    for (int i = threadIdx.x; i < 128 * 32; i += 256) {
      int r = i >> 5, kk = i & 31;
      sA[kk][r] = A[(size_t)(m0 + r) * K + k0 + kk];
    }
    for (int i = threadIdx.x; i < 32 * 64; i += 256) {
      int kk = i >> 6, c = i & 63;
      sB[kk][c] = W[(size_t)(k0 + kk) * Nw + n0 + c];
    }
    __syncthreads();
#pragma unroll
    for (int kk = 0; kk < 32; ++kk) {
      float4 a0 = *(const float4*)&sA[kk][ty * 8];
      float4 a1 = *(const float4*)&sA[kk][ty * 8 + 4];
      float4 b0 = *(const float4*)&sB[kk][tx * 4];
      float ar[8] = {a0.x, a0.y, a0.z, a0.w, a1.x, a1.y, a1.z, a1.w};
      float br[4] = {b0.x, b0.y, b0.z, b0.w};
#pragma unroll
      for (int i2 = 0; i2 < 8; ++i2)
#pragma unroll
        for (int j2 = 0; j2 < 4; ++j2)
          acc[i2][j2] = fmaf(ar[i2], br[j2], acc[i2][j2]);
    }
    __syncthreads();
  }
#pragma unroll
  for (int i2 = 0; i2 < 8; ++i2) {
    float4 st = make_float4(acc[i2][0], acc[i2][1], acc[i2][2], acc[i2][3]);
    *(float4*)&C[(size_t)(m0 + ty * 8 + i2) * Nw + n0 + tx * 4] = st;
  }
}

// ------------------------- per-batch persistent kernel ---------------------
__global__ __launch_bounds__(1024) void persist_kernel(
    const float* __restrict__ inp, const float* __restrict__ hid,
    const float* __restrict__ mem_bias,
    const float* __restrict__ icatC, const float* __restrict__ icatW,
    const float* __restrict__ addrW, const float* __restrict__ addrWT,
    const float* __restrict__ atten,
    const float* __restrict__ Wh2w,
    const float* __restrict__ Wh2g, const float* __restrict__ Wi2g,
    const float* __restrict__ Wr2g,
    const float* __restrict__ Wh2ab, const float* __restrict__ Wi2ab,
    const float* __restrict__ Wr2ab,
    const float* __restrict__ Wh2c, const float* __restrict__ Wr2c,
    const float* __restrict__ Wh2tau, const float* __restrict__ b_h2tau,
    const float* __restrict__ Wh2m, const float* __restrict__ Wm2w,
    const float* __restrict__ Wu2w,
    float* __restrict__ out) {
  const int b = blockIdx.x, tid = threadIdx.x;
  const int lane = tid & 63, wv = tid >> 6;   // 16 waves
  __shared__ float hL[HD], ccL[HD];
  __shared__ float scratch[1024];
  __shared__ float zl[NS];
  __shared__ float w_sumL[NS];
  __shared__ float u2wL[AC], biasL[AC], attL[AC], rsL[AC];
  __shared__ float embL[ID];
  __shared__ float valHistL[LL][CCd];     // 16 KB
  __shared__ float valWHistL[LL][AC];     // 32 KB
  __shared__ int   lastWriterL[NS];
  __shared__ int   writePosL[LL];
  __shared__ float redv[16]; __shared__ int redi[16];
  __shared__ float s_fio[3], s_ab[2];
  __shared__ float s_tau, s_zmax, s_ws; __shared__ int s_ns;

  // per-block init (all state block-private)
  hL[tid] = hid[(size_t)b * HD + tid];
  ccL[tid] = 0.0f;
  if (tid < NS) { w_sumL[tid] = 0.0f; lastWriterL[tid] = -1; }
  if (tid < AC) attL[tid] = atten[tid];
  uint32_t k1a, k1b, k2a, k2b;
  threefry2x32(0u, 42u, 0u, 0u, k1a, k1b);
  threefry2x32(0u, 42u, 0u, 1u, k2a, k2b);
  __syncthreads();

  for (int t = 0; t < LL; ++t) {
    const size_t row = (size_t)t * BB + b;
    if (tid < ID) embL[tid] = inp[row * ID + tid];

    // ---- u2w = LayerNorm(w_sum) @ Wu2w ----
    {
      float v = (tid < NS) ? w_sumL[tid] : 0.0f;
      float s1 = v;
      for (int off = 32; off; off >>= 1) s1 += __shfl_down(s1, off, 64);
      if (lane == 0) redv[wv] = s1;
      __syncthreads();
      float mu;
      { float a = 0; for (int i = 0; i < 8; ++i) a += redv[i]; mu = a / (float)NS; }
      __syncthreads();
      float d = (tid < NS) ? (v - mu) * (v - mu) : 0.0f;
      for (int off = 32; off; off >>= 1) d += __shfl_down(d, off, 64);
      if (lane == 0) redv[wv] = d;
      __syncthreads();
      float var;
      { float a = 0; for (int i = 0; i < 8; ++i) a += redv[i]; var = a / (float)NS; }
      float rsq = rsqrtf(var + 1e-5f);
      if (tid < NS) zl[tid] = (v - mu) * rsq;
      __syncthreads();
      { int m = tid & 255, q = tid >> 8; float acc = 0; int k0 = q * 128;
#pragma unroll 4
        for (int k = k0; k < k0 + 128; ++k) acc = fmaf(zl[k], Wu2w[(size_t)k * AC + m], acc);
        scratch[tid] = acc; }
      __syncthreads();
      if (tid < AC) u2wL[tid] = scratch[tid] + scratch[tid + 256] + scratch[tid + 512] + scratch[tid + 768];
      __syncthreads();
    }

    // ---- bias = h@W_h2w + icatW + u2w ----
    { int m = tid & 255, q = tid >> 8; float acc = 0; int k0 = q * 256;
#pragma unroll 4
      for (int k = k0; k < k0 + 256; ++k) acc = fmaf(hL[k], Wh2w[(size_t)k * AC + m], acc);
      scratch[tid] = acc; }
    __syncthreads();
    if (tid < AC)
      biasL[tid] = scratch[tid] + scratch[tid + 256] + scratch[tid + 512] + scratch[tid + 768]
                 + icatW[row * AC + tid] + u2wL[tid];
    __syncthreads();

    // ---- logits over 512 slots (static addrW^T pass) ----
    { int n = tid & 511, h2 = tid >> 9; float p = 0; int k0 = h2 * 128;
#pragma unroll 4
      for (int k = k0; k < k0 + 128; ++k)
        p = fmaf(fast_tanh(biasL[k] + addrWT[(size_t)k * NS + n]), attL[k], p);
      scratch[tid] = p; }
    __syncthreads();
    if (tid < NS) zl[tid] = scratch[tid] + scratch[tid + 512];
    __syncthreads();
    // correction pass for written slots (state all in LDS)
    for (int j = wv; j < t; j += 16) {
      int n2 = writePosL[j];
      int s = lastWriterL[n2];
      float q = 0;
      for (int k = lane; k < AC; k += 64)
        q = fmaf(fast_tanh(biasL[k] + addrW[(size_t)n2 * AC + k] + valWHistL[s][k]), attL[k], q);
      for (int off = 32; off; off >>= 1) q += __shfl_down(q, off, 64);
      if (lane == 0) zl[n2] = q;
    }
    __syncthreads();

    // ---- gumbel + argmax (waves 0-7) ∥ tau (wave 8) ----
    float zg = -1e30f;
    if (tid < NS) {
      uint32_t gi = (uint32_t)(row * NS + tid);
      uint32_t o0, o1; threefry2x32(k1a, k1b, 0u, gi, o0, o1);
      zg = zl[tid] + bits_to_gumbel(o0 ^ o1);
    }
    { float v = zg; int ix = (tid < NS) ? tid : 0x7fffffff;
      for (int off = 32; off; off >>= 1) {
        float vo = __shfl_down(v, off, 64); int io = __shfl_down(ix, off, 64);
        if (vo > v || (vo == v && io < ix)) { v = vo; ix = io; }
      }
      if (lane == 0) { redv[wv] = v; redi[wv] = ix; } }
    if (wv == 8) {
      float x = 0;
      for (int k = lane; k < HD; k += 64) x = fmaf(hL[k], Wh2tau[k], x);
      for (int off = 32; off; off >>= 1) x += __shfl_down(x, off, 64);
      if (lane == 0) {
        x += b_h2tau[0];
        s_tau = fmaxf(x, 0.0f) + log1pf(expf(-fabsf(x))) + 1.0f;
      }
    }
    __syncthreads();
    if (tid == 0) {
      float v = redv[0]; int ix = redi[0];
      for (int i = 1; i < 8; ++i)
        if (redv[i] > v || (redv[i] == v && redi[i] < ix)) { v = redv[i]; ix = redi[i]; }
      s_zmax = v; s_ns = ix;
    }
    __syncthreads();

    // ---- softmax denominator -> w* ----
    { float e = (tid < NS) ? expf((zg - s_zmax) / s_tau) : 0.0f;
      for (int off = 32; off; off >>= 1) e += __shfl_down(e, off, 64);
      if (lane == 0) redv[wv] = e; }
    __syncthreads();
    if (tid == 0) {
      float D = 0; for (int i = 0; i < 8; ++i) D += redv[i];
      float ystar = 1.0f / D;
      s_ws = (1.0f - ystar) + ystar;
    }
    __syncthreads();
    const int ns = s_ns; const float ws = s_ws;

    // ---- r = w* . mem[ns] ----
    if (tid < AC) {
      int sW = lastWriterL[ns];
      float mv = (tid < AA) ? mem_bias[(size_t)ns * AC + tid]
               : ((sW >= 0) ? valHistL[sW][tid - AA] : 0.0f);
      rsL[tid] = ws * mv;
    }
    __syncthreads();

    // ---- gates (waves 0-2) and alpha/beta (waves 3-4) ----
    if (wv < 3) {
      int j = wv; float p = 0;
      for (int k = lane; k < HD; k += 64) p = fmaf(hL[k], Wh2g[k * 3 + j], p);
      for (int k = lane; k < ID; k += 64) p = fmaf(embL[k], Wi2g[k * 3 + j], p);
      for (int k = lane; k < AC; k += 64) p = fmaf(rsL[k], Wr2g[k * 3 + j], p);
      for (int off = 32; off; off >>= 1) p += __shfl_down(p, off, 64);
      if (lane == 0) s_fio[j] = 1.0f / (1.0f + expf(-p));
    } else if (wv < 5) {
      int j = wv - 3; float p = 0;
      for (int k = lane; k < HD; k += 64) p = fmaf(hL[k], Wh2ab[k * 2 + j], p);
      for (int k = lane; k < ID; k += 64) p = fmaf(embL[k], Wi2ab[k * 2 + j], p);
      for (int k = lane; k < AC; k += 64) p = fmaf(rsL[k], Wr2ab[k * 2 + j], p);
      for (int off = 32; off; off >>= 1) p += __shfl_down(p, off, 64);
      if (lane == 0) {
        uint32_t i1 = (uint32_t)((row * 2 + j) * 2);
        uint32_t o0, o1;
        threefry2x32(k2a, k2b, 0u, i1, o0, o1);     float g1 = bits_to_gumbel(o0 ^ o1);
        threefry2x32(k2a, k2b, 0u, i1 + 1, o0, o1); float g2 = bits_to_gumbel(o0 ^ o1);
        s_ab[j] = (p + g1 - g2) > 0.0f ? 1.0f : 0.0f;
      }
    }
    __syncthreads();
    const float fg = s_fio[0], ig = s_fio[1], og = s_fio[2];
    const float alpha = s_ab[0], beta = s_ab[1];

    // ---- c_tilde / cc / h  (beta==0 skips the 4MB W_h2c stream) ----
    float arg = icatC[row * HD + tid];
    if (alpha != 0.0f) {
      float rp = 0;
      const float* wc = Wr2c + tid;
#pragma unroll 4
      for (int k = 0; k < AC; ++k) rp = fmaf(rsL[k], wc[(size_t)k * HD], rp);
      arg += rp;
    }
    if (beta != 0.0f) {
      float hp = 0;
      const float* wc = Wh2c + tid;
#pragma unroll 4
      for (int k = 0; k < HD; ++k) hp = fmaf(hL[k], wc[(size_t)k * HD], hp);
      arg += hp;
    }
    float ct = tanhf(arg);
    float cn = fg * ccL[tid] + ig * ct;
    float hn = og * tanhf(cn);
    ccL[tid] = cn;
    out[row * HD + tid] = hn;
    __syncthreads();          // all hL readers done
    hL[tid] = hn;
    __syncthreads();

    // ---- val / valW / bookkeeping (skip at last step) ----
    if (t + 1 < LL) {
      { int c = tid & 127, q = tid >> 7; float acc = 0; int k0 = q * 128;
#pragma unroll 4
        for (int k = k0; k < k0 + 128; ++k) acc = fmaf(hL[k], Wh2m[(size_t)k * CCd + c], acc);
        scratch[tid] = acc; }
      __syncthreads();
      if (tid < CCd) {
        float val = 0;
#pragma unroll
        for (int i = 0; i < 8; ++i) val += scratch[tid + i * 128];
        valHistL[t][tid] = val;
      }
      __syncthreads();
      { int m = tid & 255, q = tid >> 8; float acc = 0; int c0 = q * 32;
#pragma unroll 4
        for (int c = c0; c < c0 + 32; ++c)
          acc = fmaf(valHistL[t][c], Wm2w[(size_t)(AA + c) * AC + m], acc);
        scratch[tid] = acc; }
      __syncthreads();
      if (tid < AC)
        valWHistL[t][tid] = scratch[tid] + scratch[tid + 256] + scratch[tid + 512] + scratch[tid + 768];
      if (tid == 0) {
        int pos = (t < 16) ? t * LL : ns;     // ts = t*32 < 512 iff t < 16
        writePosL[t] = pos;
        lastWriterL[pos] = t;
        w_sumL[ns] += ws;
      }
      __syncthreads();
    }
  }
}

// ------------------------------ host ---------------------------------------
extern "C" void kernel_launch(void* const* d_in, const int* in_sizes, int n_in,
                              void* d_out, int out_size, void* d_ws, size_t ws_size,
                              hipStream_t stream) {
  const float* inp      = (const float*)d_in[0];
  const float* hid      = (const float*)d_in[1];
  const float* mem_bias = (const float*)d_in[2];
  const float* W_h2w    = (const float*)d_in[3];
  const float* W_i2w    = (const float*)d_in[4];
  const float* W_m2w    = (const float*)d_in[5];
  const float* W_u2w    = (const float*)d_in[6];
  const float* W_h2g    = (const float*)d_in[7];
  const float* W_i2g    = (const float*)d_in[8];
  const float* W_r2g    = (const float*)d_in[9];
  const float* W_h2ab   = (const float*)d_in[10];
  const float* W_i2ab   = (const float*)d_in[11];
  const float* W_r2ab   = (const float*)d_in[12];
  const float* W_h2c    = (const float*)d_in[13];
  const float* W_i2c    = (const float*)d_in[14];
  const float* W_r2c    = (const float*)d_in[15];
  const float* atten    = (const float*)d_in[16];
  const float* W_h2tau  = (const float*)d_in[17];
  const float* b_h2tau  = (const float*)d_in[18];
  const float* W_h2m    = (const float*)d_in[19];
  float* out = (float*)d_out;

  char* base = (char*)d_ws;
  size_t off = 0;
  auto alloc = [&](size_t elems) -> void* {
    void* p = (void*)(base + off);
    off += ((elems * 4 + 255) / 256) * 256;
    return p;
  };
  float* icatC  = (float*)alloc((size_t)LL * BB * HD);   // 16 MB: inp @ W_i2c
  float* icatW  = (float*)alloc((size_t)LL * BB * AC);   // 4 MB : inp @ W_i2w
  float* addrW  = (float*)alloc((size_t)NS * AC);
  float* addrWT = (float*)alloc((size_t)NS * AC);

  hipLaunchKernelGGL(addrw_kernel, dim3((NS * AC + 255) / 256), dim3(256), 0, stream,
                     mem_bias, W_m2w, addrW, addrWT);
  hipLaunchKernelGGL(gemm_big, dim3((LL * BB) / 128, HD / 64), dim3(256), 0, stream,
                     inp, W_i2c, icatC, ID, HD);
  hipLaunchKernelGGL(gemm_big, dim3((LL * BB) / 128, AC / 64), dim3(256), 0, stream,
                     inp, W_i2w, icatW, ID, AC);
  hipLaunchKernelGGL(persist_kernel, dim3(BB), dim3(1024), 0, stream,
                     inp, hid, mem_bias, icatC, icatW, addrW, addrWT, atten,
                     W_h2w, W_h2g, W_i2g, W_r2g, W_h2ab, W_i2ab, W_r2ab,
                     W_h2c, W_r2c, W_h2tau, b_h2tau, W_h2m, W_m2w, W_u2w,
                     out);
}

// Round 8
// 4881.380 us; speedup vs baseline: 1.9943x; 1.9943x over previous
//
#include <hip/hip_runtime.h>
#include <hip/hip_bf16.h>
#include <math.h>

// ---------------------------------------------------------------------------
// DecoderTARDIS forward, fp32 — v6: hybrid batched-GEMM + per-batch owners.
// R7 lesson: per-batch GEMV has zero reuse (4B/MAC) -> weight streams kill it;
// batching requires sync. This round: R6 sync structure, but phase A uses
// 4x3-per-thread register tiles (0.583 floats/MAC LDS vs 1.25) over 112
// GEMM blocks x 12 cols, owners do val/valW/u2w/emb in the A-window from
// their own LDS state, gates/tau read from hcat (packed into Wcat).
// 240 blocks, 84KB LDS => hardware-guaranteed 1 block/CU, fence-free barrier.
// ---------------------------------------------------------------------------

static constexpr int LL   = 32;
static constexpr int BB   = 128;
static constexpr int ID   = 512;
static constexpr int HD   = 1024;
static constexpr int NS   = 512;
static constexpr int AA   = 128;
static constexpr int CCd  = 128;
static constexpr int AC   = 256;
static constexpr int WC   = 1344;           // 112 * 12
static constexpr int COL_W0  = 1024;
static constexpr int COL_G0  = 1280;
static constexpr int COL_AB0 = 1283;
static constexpr int COL_TAU = 1285;
static constexpr int NOWN = 128;
static constexpr int NAB  = 112;
static constexpr int GRID_P = NOWN + NAB;   // 240

// ------------------------------ threefry -----------------------------------
__device__ __forceinline__ uint32_t rotl32(uint32_t x, uint32_t r) {
  return (x << r) | (x >> (32u - r));
}

__device__ __forceinline__ void threefry2x32(uint32_t k0, uint32_t k1,
                                             uint32_t x0, uint32_t x1,
                                             uint32_t& o0, uint32_t& o1) {
  uint32_t ks0 = k0, ks1 = k1, ks2 = 0x1BD11BDAu ^ k0 ^ k1;
  x0 += ks0; x1 += ks1;
#define TFR(r) { x0 += x1; x1 = rotl32(x1, r); x1 ^= x0; }
  TFR(13u) TFR(15u) TFR(26u) TFR(6u)   x0 += ks1; x1 += ks2 + 1u;
  TFR(17u) TFR(29u) TFR(16u) TFR(24u)  x0 += ks2; x1 += ks0 + 2u;
  TFR(13u) TFR(15u) TFR(26u) TFR(6u)   x0 += ks0; x1 += ks1 + 3u;
  TFR(17u) TFR(29u) TFR(16u) TFR(24u)  x0 += ks1; x1 += ks2 + 4u;
  TFR(13u) TFR(15u) TFR(26u) TFR(6u)   x0 += ks2; x1 += ks0 + 5u;
#undef TFR
  o0 = x0; o1 = x1;
}

__device__ __forceinline__ float bits_to_gumbel(uint32_t bits) {
  uint32_t v = (bits >> 9) | 0x3F800000u;
  float f = __uint_as_float(v) - 1.0f;
  if (f <= 0.0f) f = 1.17549435e-38f;
  return -logf(-logf(f));
}

__device__ __forceinline__ float fast_tanh(float x) {
  float e = __expf(2.0f * x);
  return 1.0f - 2.0f / (e + 1.0f);
}

// --------------- coherent (agent-scope, relaxed) access helpers ------------
__device__ __forceinline__ float cohl(const float* p) {
  return __hip_atomic_load(p, __ATOMIC_RELAXED, __HIP_MEMORY_SCOPE_AGENT);
}
__device__ __forceinline__ void cohs(float* p, float v) {
  __hip_atomic_store(p, v, __ATOMIC_RELAXED, __HIP_MEMORY_SCOPE_AGENT);
}
__device__ __forceinline__ float2 cohl2(const float* p) {
  unsigned long long u = __hip_atomic_load((const unsigned long long*)p,
                                           __ATOMIC_RELAXED, __HIP_MEMORY_SCOPE_AGENT);
  float2 r; __builtin_memcpy(&r, &u, 8); return r;
}
__device__ __forceinline__ void cohs2(float* p, float2 v) {
  unsigned long long u; __builtin_memcpy(&u, &v, 8);
  __hip_atomic_store((unsigned long long*)p, u, __ATOMIC_RELAXED, __HIP_MEMORY_SCOPE_AGENT);
}

// ---------------- grid barrier: relaxed atomics + vmcnt drain --------------
__device__ __forceinline__ void gbar(unsigned int* cnt, unsigned int* flag,
                                     unsigned int& epoch) {
  asm volatile("s_waitcnt vmcnt(0)" ::: "memory");
  __syncthreads();
  if (threadIdx.x == 0) {
    epoch++;
    unsigned int old = __hip_atomic_fetch_add(cnt, 1u, __ATOMIC_RELAXED,
                                              __HIP_MEMORY_SCOPE_AGENT);
    if (old == epoch * GRID_P - 1u) {
      __hip_atomic_store(flag, epoch, __ATOMIC_RELAXED, __HIP_MEMORY_SCOPE_AGENT);
    } else {
      while (__hip_atomic_load(flag, __ATOMIC_RELAXED, __HIP_MEMORY_SCOPE_AGENT) < epoch) {
        __builtin_amdgcn_s_sleep(8);
      }
    }
  }
  __syncthreads();
}

// ------------------------------ prologue -----------------------------------
__global__ void pack_wcat(const float* __restrict__ Wh2c, const float* __restrict__ Wh2w,
                          const float* __restrict__ Wh2g, const float* __restrict__ Wh2ab,
                          const float* __restrict__ Wh2tau, float* __restrict__ Wcat) {
  int idx = blockIdx.x * blockDim.x + threadIdx.x;
  if (idx >= HD * WC) return;
  int k = idx / WC, c = idx % WC;
  float v = 0.0f;
  if (c < 1024)       v = Wh2c[(size_t)k * HD + c];
  else if (c < 1280)  v = Wh2w[(size_t)k * AC + (c - 1024)];
  else if (c < 1283)  v = Wh2g[k * 3 + (c - 1280)];
  else if (c < 1285)  v = Wh2ab[k * 2 + (c - 1283)];
  else if (c == 1285) v = Wh2tau[k];
  Wcat[idx] = v;
}

__global__ void addrw_kernel(const float* __restrict__ mem_bias,
                             const float* __restrict__ Wm2w,
                             float* __restrict__ addrW, float* __restrict__ addrWT) {
  int idx = blockIdx.x * blockDim.x + threadIdx.x;
  if (idx >= NS * AC) return;
  int n = idx / AC, m = idx % AC;
  float acc = 0.0f;
  for (int k = 0; k < AA; k++) acc += mem_bias[(size_t)n * AC + k] * Wm2w[(size_t)k * AC + m];
  addrW[(size_t)n * AC + m] = acc;
  addrWT[(size_t)m * NS + n] = acc;
}

__global__ void init_kernel(const float* __restrict__ hid, float* __restrict__ hbuf,
                            unsigned int* __restrict__ bar) {
  int idx = blockIdx.x * blockDim.x + threadIdx.x;
  if (idx < BB * HD) hbuf[idx] = hid[idx];
  if (idx < 512) bar[idx] = 0u;
}

// generic fp32 GEMM: C(M x Nw) = A(M x K) @ W(K x Nw); 128x64 tile, 8x4/thr
__global__ __launch_bounds__(256) void gemm_big(const float* __restrict__ A,
                                                const float* __restrict__ W,
                                                float* __restrict__ C,
                                                int K, int Nw) {
  __shared__ float sA[32][132];
  __shared__ float sB[32][68];
  const int tx = threadIdx.x & 15, ty = threadIdx.x >> 4;
  const int m0 = blockIdx.x * 128, n0 = blockIdx.y * 64;
  float acc[8][4] = {};
  for (int k0 = 0; k0 < K; k0 += 32) {
    for (int i = threadIdx.x; i < 128 * 32; i += 256) {
      int r = i >> 5, kk = i & 31;
      sA[kk][r] = A[(size_t)(m0 + r) * K + k0 + kk];
    }
    for (int i = threadIdx.x; i < 32 * 64; i += 256) {
      int kk = i >> 6, c = i & 63;
      sB[kk][c] = W[(size_t)(k0 + kk) * Nw + n0 + c];
    }
    __syncthreads();
#pragma unroll
    for (int kk = 0; kk < 32; ++kk) {
      float4 a0 = *(const float4*)&sA[kk][ty * 8];
      float4 a1 = *(const float4*)&sA[kk][ty * 8 + 4];
      float4 b0 = *(const float4*)&sB[kk][tx * 4];
      float ar[8] = {a0.x, a0.y, a0.z, a0.w, a1.x, a1.y, a1.z, a1.w};
      float br[4] = {b0.x, b0.y, b0.z, b0.w};
#pragma unroll
      for (int i2 = 0; i2 < 8; ++i2)
#pragma unroll
        for (int j2 = 0; j2 < 4; ++j2)
          acc[i2][j2] = fmaf(ar[i2], br[j2], acc[i2][j2]);
    }
    __syncthreads();
  }
#pragma unroll
  for (int i2 = 0; i2 < 8; ++i2) {
    float4 st = make_float4(acc[i2][0], acc[i2][1], acc[i2][2], acc[i2][3]);
    *(float4*)&C[(size_t)(m0 + ty * 8 + i2) * Nw + n0 + tx * 4] = st;
  }
}

// ------------------------------ persistent kernel --------------------------
struct AS { float w[12][1032]; float hst[128][68]; };   // 49.5 + 34.8 KB
struct OS {
  float hL[HD]; float ccL[HD];
  float embL[ID];
  float w_sumL[NS]; float zl[NS];
  float u2wL[AC]; float biasL[AC]; float attL[AC]; float rsL[AC];
  float valHistL[LL][CCd];
  float valWHistL[LL][AC];
  float scratch[512];
  int   lastWriterL[NS];
  int   writePosL[LL];
};
union SU { AS a; OS o; };

__global__ __launch_bounds__(512) void persist_kernel(
    const float* __restrict__ inp, const float* __restrict__ hid,
    const float* __restrict__ mem_bias,
    const float* __restrict__ icatC, const float* __restrict__ icatW,
    const float* __restrict__ Wcat,
    const float* __restrict__ addrW, const float* __restrict__ addrWT,
    const float* __restrict__ atten,
    const float* __restrict__ Wi2g, const float* __restrict__ Wr2g,
    const float* __restrict__ Wi2ab, const float* __restrict__ Wr2ab,
    const float* __restrict__ Wr2c,
    const float* __restrict__ b_h2tau,
    const float* __restrict__ Wh2m, const float* __restrict__ Wm2w,
    const float* __restrict__ Wu2w,
    float* hbuf, float* hcat,
    unsigned int* bar_cnt, unsigned int* bar_flag,
    float* __restrict__ out) {
  const int blk = blockIdx.x, tid = threadIdx.x;
  const int lane = tid & 63, wv = tid >> 6;
  __shared__ SU sm;
  __shared__ float redv[8]; __shared__ int redi[8];
  __shared__ float s_fio[3], s_ab[2], s_tau, s_zmax, s_ws; __shared__ int s_ns;
  unsigned int epoch = 0;

  uint32_t k1a, k1b, k2a, k2b;
  threefry2x32(0u, 42u, 0u, 0u, k1a, k1b);
  threefry2x32(0u, 42u, 0u, 1u, k2a, k2b);

  const bool owner = (blk < NOWN);
  const int b = blk;                 // owner's batch
  const int an0 = (blk - NOWN) * 12; // A-block's first col

  if (owner) {
    for (int i = tid; i < HD; i += 512) {
      sm.o.hL[i] = hid[(size_t)b * HD + i];
      sm.o.ccL[i] = 0.0f;
    }
    if (tid < NS) { sm.o.w_sumL[tid] = 0.0f; sm.o.lastWriterL[tid] = -1; }
    if (tid < AC) { sm.o.attL[tid] = atten[tid]; sm.o.u2wL[tid] = 0.0f; }
  } else {
    // one-time: this block's 12 Wcat cols -> LDS (row-efficient load order)
    for (int i = tid; i < 12 * 1024; i += 512) {
      int k = i / 12, c = i - k * 12;
      sm.a.w[c][k] = Wcat[(size_t)k * WC + an0 + c];
    }
  }
  __syncthreads();

  for (int t = 0; t < LL; ++t) {
    const size_t row = (size_t)t * BB + b;
    // =================== window A ======================================
    if (!owner) {
      const int cg = tid & 3, rowg = tid >> 2;   // compute threads: tid<128
      float acc[4][3] = {};
      float2 pre[8];
#pragma unroll
      for (int ii = 0; ii < 8; ++ii) {           // prefetch chunk 0
        int f = ii * 512 + tid, r2 = f >> 5, k2 = f & 31;
        pre[ii] = cohl2(&hbuf[(size_t)r2 * HD + k2 * 2]);
      }
      for (int kc = 0; kc < HD; kc += 64) {
        __syncthreads();
#pragma unroll
        for (int ii = 0; ii < 8; ++ii) {
          int f = ii * 512 + tid, r2 = f >> 5, k2 = f & 31;
          *(float2*)&sm.a.hst[r2][k2 * 2] = pre[ii];
        }
        __syncthreads();
        if (kc + 64 < HD) {
#pragma unroll
          for (int ii = 0; ii < 8; ++ii) {
            int f = ii * 512 + tid, r2 = f >> 5, k2 = f & 31;
            pre[ii] = cohl2(&hbuf[(size_t)r2 * HD + kc + 64 + k2 * 2]);
          }
        }
        if (tid < 128) {
#pragma unroll
          for (int k4 = 0; k4 < 16; ++k4) {
            float4 w0 = *(const float4*)&sm.a.w[cg * 3 + 0][kc + k4 * 4];
            float4 w1 = *(const float4*)&sm.a.w[cg * 3 + 1][kc + k4 * 4];
            float4 w2 = *(const float4*)&sm.a.w[cg * 3 + 2][kc + k4 * 4];
#pragma unroll
            for (int j = 0; j < 4; ++j) {
              float4 h4 = *(const float4*)&sm.a.hst[rowg + 32 * j][k4 * 4];
              acc[j][0] = fmaf(h4.x, w0.x, fmaf(h4.y, w0.y, fmaf(h4.z, w0.z, fmaf(h4.w, w0.w, acc[j][0]))));
              acc[j][1] = fmaf(h4.x, w1.x, fmaf(h4.y, w1.y, fmaf(h4.z, w1.z, fmaf(h4.w, w1.w, acc[j][1]))));
              acc[j][2] = fmaf(h4.x, w2.x, fmaf(h4.y, w2.y, fmaf(h4.z, w2.z, fmaf(h4.w, w2.w, acc[j][2]))));
            }
          }
        }
      }
      if (tid < 128) {
#pragma unroll
        for (int j = 0; j < 4; ++j)
#pragma unroll
          for (int c = 0; c < 3; ++c)
            cohs(&hcat[(size_t)(rowg + 32 * j) * WC + an0 + cg * 3 + c], acc[j][c]);
      }
    } else {
      // owner A-window: emb load, val/valW for t-1, u2w for t (own LDS state)
      if (tid < ID) sm.o.embL[tid] = inp[row * ID + tid];
      if (t > 0) {
        { int c = tid & 127, q = tid >> 7; float a3 = 0; int k0 = q * 256;
#pragma unroll 4
          for (int k = k0; k < k0 + 256; ++k) a3 = fmaf(sm.o.hL[k], Wh2m[(size_t)k * CCd + c], a3);
          sm.o.scratch[tid] = a3; }
        __syncthreads();
        if (tid < CCd)
          sm.o.valHistL[t - 1][tid] = sm.o.scratch[tid] + sm.o.scratch[tid + 128] +
                                      sm.o.scratch[tid + 256] + sm.o.scratch[tid + 384];
        __syncthreads();
        { int m = tid & 255, q = tid >> 8; float a3 = 0; int c0 = q * 64;
#pragma unroll 4
          for (int c = c0; c < c0 + 64; ++c)
            a3 = fmaf(sm.o.valHistL[t - 1][c], Wm2w[(size_t)(AA + c) * AC + m], a3);
          sm.o.scratch[tid] = a3; }
        __syncthreads();
        if (tid < AC) sm.o.valWHistL[t - 1][tid] = sm.o.scratch[tid] + sm.o.scratch[tid + 256];
        __syncthreads();
      }
      // u2w = LayerNorm(w_sum) @ Wu2w
      {
        float v = sm.o.w_sumL[tid];       // tid < 512 == NS
        float s1 = v;
        for (int off = 32; off; off >>= 1) s1 += __shfl_down(s1, off, 64);
        if (lane == 0) redv[wv] = s1;
        __syncthreads();
        float mu = 0; for (int i = 0; i < 8; ++i) mu += redv[i]; mu /= (float)NS;
        __syncthreads();
        float d = (v - mu) * (v - mu);
        for (int off = 32; off; off >>= 1) d += __shfl_down(d, off, 64);
        if (lane == 0) redv[wv] = d;
        __syncthreads();
        float var = 0; for (int i = 0; i < 8; ++i) var += redv[i]; var /= (float)NS;
        float rsq = rsqrtf(var + 1e-5f);
        sm.o.zl[tid] = (v - mu) * rsq;
        __syncthreads();
        { int m = tid & 255, q = tid >> 8; float a3 = 0; int k0 = q * 256;
#pragma unroll 4
          for (int k = k0; k < k0 + 256; ++k) a3 = fmaf(sm.o.zl[k], Wu2w[(size_t)k * AC + m], a3);
          sm.o.scratch[tid] = a3; }
        __syncthreads();
        if (tid < AC) sm.o.u2wL[tid] = sm.o.scratch[tid] + sm.o.scratch[tid + 256];
      }
    }
    gbar(bar_cnt, bar_flag, epoch);

    // =================== window LS (owners) ============================
    if (owner) {
      if (tid < AC)
        sm.o.biasL[tid] = cohl(&hcat[(size_t)b * WC + COL_W0 + tid]) +
                          icatW[row * AC + tid] + sm.o.u2wL[tid];
      __syncthreads();
      {  // logits, n = tid
        float p = 0.0f;
        const float* awc = addrWT + tid;
#pragma unroll 8
        for (int k = 0; k < AC; ++k)
          p = fmaf(fast_tanh(sm.o.biasL[k] + awc[(size_t)k * NS]), sm.o.attL[k], p);
        sm.o.zl[tid] = p;
      }
      __syncthreads();
      for (int j = wv; j < t; j += 8) {   // corrections for written slots
        int n2 = sm.o.writePosL[j];
        int s = sm.o.lastWriterL[n2];
        float q = 0.0f;
        for (int k = lane; k < AC; k += 64)
          q = fmaf(fast_tanh(sm.o.biasL[k] + addrW[(size_t)n2 * AC + k] + sm.o.valWHistL[s][k]),
                   sm.o.attL[k], q);
        for (int off = 32; off; off >>= 1) q += __shfl_down(q, off, 64);
        if (lane == 0) sm.o.zl[n2] = q;
      }
      __syncthreads();
      float zg;
      {
        uint32_t gi = (uint32_t)(row * NS + tid);
        uint32_t o0, o1; threefry2x32(k1a, k1b, 0u, gi, o0, o1);
        zg = sm.o.zl[tid] + bits_to_gumbel(o0 ^ o1);
      }
      { float v = zg; int ix = tid;
        for (int off = 32; off; off >>= 1) {
          float vo = __shfl_down(v, off, 64); int io = __shfl_down(ix, off, 64);
          if (vo > v || (vo == v && io < ix)) { v = vo; ix = io; }
        }
        if (lane == 0) { redv[wv] = v; redi[wv] = ix; } }
      __syncthreads();
      if (tid == 0) {
        float v = redv[0]; int ix = redi[0];
        for (int i = 1; i < 8; ++i)
          if (redv[i] > v || (redv[i] == v && redi[i] < ix)) { v = redv[i]; ix = redi[i]; }
        s_zmax = v; s_ns = ix;
        float x = cohl(&hcat[(size_t)b * WC + COL_TAU]) + b_h2tau[0];
        s_tau = fmaxf(x, 0.0f) + log1pf(expf(-fabsf(x))) + 1.0f;
      }
      __syncthreads();
      { float e = expf((zg - s_zmax) / s_tau);
        for (int off = 32; off; off >>= 1) e += __shfl_down(e, off, 64);
        if (lane == 0) redv[wv] = e; }
      __syncthreads();
      if (tid == 0) {
        float D = 0; for (int i = 0; i < 8; ++i) D += redv[i];
        float ystar = 1.0f / D;
        s_ws = (1.0f - ystar) + ystar;
      }
      __syncthreads();
      const int ns = s_ns; const float ws = s_ws;
      if (tid < AC) {
        int sW = sm.o.lastWriterL[ns];
        float mv = (tid < AA) ? mem_bias[(size_t)ns * AC + tid]
                 : ((sW >= 0) ? sm.o.valHistL[sW][tid - AA] : 0.0f);
        sm.o.rsL[tid] = ws * mv;
      }
      __syncthreads();
      // bookkeeping (wave 0 lane 0) || gates (waves 1-3) || ab (waves 4-5)
      if (tid == 0) {
        int pos = (t < 16) ? t * LL : ns;
        sm.o.writePosL[t] = pos;
        sm.o.lastWriterL[pos] = t;
        sm.o.w_sumL[ns] += ws;
      }
      if (wv >= 1 && wv <= 3) {
        int j = wv - 1; float p = 0.0f;
        for (int k = lane; k < ID; k += 64) p = fmaf(sm.o.embL[k], Wi2g[k * 3 + j], p);
        for (int k = lane; k < AC; k += 64) p = fmaf(sm.o.rsL[k], Wr2g[k * 3 + j], p);
        for (int off = 32; off; off >>= 1) p += __shfl_down(p, off, 64);
        if (lane == 0) {
          float x = p + cohl(&hcat[(size_t)b * WC + COL_G0 + j]);
          s_fio[j] = 1.0f / (1.0f + expf(-x));
        }
      } else if (wv >= 4 && wv <= 5) {
        int j = wv - 4; float p = 0.0f;
        for (int k = lane; k < ID; k += 64) p = fmaf(sm.o.embL[k], Wi2ab[k * 2 + j], p);
        for (int k = lane; k < AC; k += 64) p = fmaf(sm.o.rsL[k], Wr2ab[k * 2 + j], p);
        for (int off = 32; off; off >>= 1) p += __shfl_down(p, off, 64);
        if (lane == 0) {
          float x = p + cohl(&hcat[(size_t)b * WC + COL_AB0 + j]);
          uint32_t i1 = (uint32_t)((row * 2 + j) * 2);
          uint32_t o0, o1;
          threefry2x32(k2a, k2b, 0u, i1, o0, o1);     float g1 = bits_to_gumbel(o0 ^ o1);
          threefry2x32(k2a, k2b, 0u, i1 + 1, o0, o1); float g2 = bits_to_gumbel(o0 ^ o1);
          s_ab[j] = (x + g1 - g2) > 0.0f ? 1.0f : 0.0f;
        }
      }
      __syncthreads();
      const float fg = s_fio[0], ig = s_fio[1], og = s_fio[2];
      const float alpha = s_ab[0], beta = s_ab[1];
      const int c0 = tid * 2;
      {
        float rc0 = 0.0f, rc1 = 0.0f;
        if (alpha != 0.0f) {
#pragma unroll 4
          for (int k = 0; k < AC; ++k) {
            float rk = sm.o.rsL[k];
            float2 w2 = *(const float2*)&Wr2c[(size_t)k * HD + c0];
            rc0 = fmaf(rk, w2.x, rc0); rc1 = fmaf(rk, w2.y, rc1);
          }
        }
        float2 hc2 = (beta != 0.0f) ? cohl2(&hcat[(size_t)b * WC + c0]) : make_float2(0.f, 0.f);
        float2 ic2 = *(const float2*)&icatC[row * HD + c0];
        float a0 = beta * hc2.x + ic2.x + alpha * rc0;
        float a1 = beta * hc2.y + ic2.y + alpha * rc1;
        float cn0 = fg * sm.o.ccL[c0] + ig * tanhf(a0);
        float cn1 = fg * sm.o.ccL[c0 + 1] + ig * tanhf(a1);
        float hn0 = og * tanhf(cn0), hn1 = og * tanhf(cn1);
        sm.o.ccL[c0] = cn0; sm.o.ccL[c0 + 1] = cn1;
        sm.o.hL[c0] = hn0; sm.o.hL[c0 + 1] = hn1;
        *(float2*)&out[row * HD + c0] = make_float2(hn0, hn1);
        if (t + 1 < LL) cohs2(&hbuf[(size_t)b * HD + c0], make_float2(hn0, hn1));
      }
      __syncthreads();
    }
    if (t + 1 < LL) gbar(bar_cnt, bar_flag, epoch);
  }
}

// ------------------------------ host ---------------------------------------
extern "C" void kernel_launch(void* const* d_in, const int* in_sizes, int n_in,
                              void* d_out, int out_size, void* d_ws, size_t ws_size,
                              hipStream_t stream) {
  const float* inp      = (const float*)d_in[0];
  const float* hid      = (const float*)d_in[1];
  const float* mem_bias = (const float*)d_in[2];
  const float* W_h2w    = (const float*)d_in[3];
  const float* W_i2w    = (const float*)d_in[4];
  const float* W_m2w    = (const float*)d_in[5];
  const float* W_u2w    = (const float*)d_in[6];
  const float* W_h2g    = (const float*)d_in[7];
  const float* W_i2g    = (const float*)d_in[8];
  const float* W_r2g    = (const float*)d_in[9];
  const float* W_h2ab   = (const float*)d_in[10];
  const float* W_i2ab   = (const float*)d_in[11];
  const float* W_r2ab   = (const float*)d_in[12];
  const float* W_h2c    = (const float*)d_in[13];
  const float* W_i2c    = (const float*)d_in[14];
  const float* W_r2c    = (const float*)d_in[15];
  const float* atten    = (const float*)d_in[16];
  const float* W_h2tau  = (const float*)d_in[17];
  const float* b_h2tau  = (const float*)d_in[18];
  const float* W_h2m    = (const float*)d_in[19];
  float* out = (float*)d_out;

  char* base = (char*)d_ws;
  size_t off = 0;
  auto alloc = [&](size_t elems) -> void* {
    void* p = (void*)(base + off);
    off += ((elems * 4 + 255) / 256) * 256;
    return p;
  };
  float* icatC  = (float*)alloc((size_t)LL * BB * HD);   // inp @ W_i2c
  float* icatW  = (float*)alloc((size_t)LL * BB * AC);   // inp @ W_i2w
  float* Wcat   = (float*)alloc((size_t)HD * WC);
  float* addrW  = (float*)alloc((size_t)NS * AC);
  float* addrWT = (float*)alloc((size_t)NS * AC);
  float* hbuf   = (float*)alloc((size_t)BB * HD);
  float* hcat   = (float*)alloc((size_t)BB * WC);
  unsigned int* bar = (unsigned int*)alloc(512);   // [0]=counter, [256]=flag

  hipLaunchKernelGGL(pack_wcat, dim3((HD * WC + 255) / 256), dim3(256), 0, stream,
                     W_h2c, W_h2w, W_h2g, W_h2ab, W_h2tau, Wcat);
  hipLaunchKernelGGL(addrw_kernel, dim3((NS * AC + 255) / 256), dim3(256), 0, stream,
                     mem_bias, W_m2w, addrW, addrWT);
  hipLaunchKernelGGL(init_kernel, dim3((BB * HD + 255) / 256), dim3(256), 0, stream,
                     hid, hbuf, bar);
  hipLaunchKernelGGL(gemm_big, dim3((LL * BB) / 128, HD / 64), dim3(256), 0, stream,
                     inp, W_i2c, icatC, ID, HD);
  hipLaunchKernelGGL(gemm_big, dim3((LL * BB) / 128, AC / 64), dim3(256), 0, stream,
                     inp, W_i2w, icatW, ID, AC);
  hipLaunchKernelGGL(persist_kernel, dim3(GRID_P), dim3(512), 0, stream,
                     inp, hid, mem_bias, icatC, icatW, Wcat, addrW, addrWT, atten,
                     W_i2g, W_r2g, W_i2ab, W_r2ab, W_r2c, b_h2tau,
                     W_h2m, W_m2w, W_u2w,
                     hbuf, hcat, bar, bar + 256, out);
}